// Round 2
// baseline (517.337 us; speedup 1.0000x reference)
//
#include <hip/hip_runtime.h>

typedef __attribute__((ext_vector_type(8))) short short8;
typedef __attribute__((ext_vector_type(4))) float f32x4;

#define MAXNORM 0.996f        // (1 - 4e-3)/sqrt(c), c=1
#define MINNORM 1e-15f
#define ATEPS   (1.0f - 1e-7f)

__device__ __forceinline__ float frcp(float x) { return __builtin_amdgcn_rcpf(x); }
// artanh on [0, 1-1e-7] with the reference clamp folded in
__device__ __forceinline__ float artanh_c(float z) {
    z = fminf(z, ATEPS);
    return 0.5f * __logf((1.0f + z) * frcp(1.0f - z));
}
// tanh for a >= 0
__device__ __forceinline__ float tanh_pos(float a) {
    float e = __expf(-2.0f * a);
    return (1.0f - e) * frcp(1.0f + e);
}
// fp32 -> bf16 bits, round-to-nearest-even
__device__ __forceinline__ unsigned short f2bf(float f) {
    union { float f; unsigned u; } v; v.f = f;
    unsigned r = v.u + 0x7FFFu + ((v.u >> 16) & 1u);
    return (unsigned short)(r >> 16);
}

__global__ __launch_bounds__(256) void blinear_kernel(
    const float* __restrict__ Xf,   // [N,128] fp32
    const float* __restrict__ Wf,   // [128,128] fp32
    const float* __restrict__ Bf,   // [128] fp32
    float* __restrict__ Out)        // [N,128] fp32
{
    const int lane = threadIdx.x & 63;
    const int wave = threadIdx.x >> 6;
    const int c = lane & 15;   // col within 16x16 tile / A-row selector
    const int q = lane >> 4;   // quad (k-group selector; row-group in C layout)
    const long rowbase = (long)blockIdx.x * 128 + wave * 32;   // 32 rows per wave

    // ---- bias prologue (per-wave, redundant, no LDS) ----
    // hyp_bias = proj(expmap0(b)) = fb * b   (b == 0 in this problem, kept general)
    float b0 = Bf[lane];
    float b1 = Bf[64 + lane];
    float bn2 = b0 * b0 + b1 * b1;
    #pragma unroll
    for (int m = 1; m <= 32; m <<= 1) bn2 += __shfl_xor(bn2, m);
    float bn = fmaxf(sqrtf(bn2), MINNORM);
    float tb = tanh_pos(bn);
    float fb = fminf(tb, MAXNORM) * frcp(bn);
    float hb2 = fb * fb * bn2;                 // sum(hb^2)
    float hbv[8];                              // hb at cols nt*16 + c
    #pragma unroll
    for (int nt = 0; nt < 8; ++nt) hbv[nt] = fb * Bf[nt * 16 + c];

    // ---- A fragments: X read once (fp32), packed to bf16; Sum(x^2) in fp32 ----
    // A layout: A[m = lane&15][k = quad*8 + j]
    short8 afr[2][4];
    float xq[2] = {0.0f, 0.0f};
    #pragma unroll
    for (int t = 0; t < 2; ++t) {
        const float* xrow = Xf + (rowbase + t * 16 + c) * 128;
        #pragma unroll
        for (int ks = 0; ks < 4; ++ks) {
            f32x4 a0 = *(const f32x4*)(xrow + ks * 32 + q * 8);
            f32x4 a1 = *(const f32x4*)(xrow + ks * 32 + q * 8 + 4);
            short8 s;
            #pragma unroll
            for (int j = 0; j < 4; ++j) {
                float v0 = a0[j], v1 = a1[j];
                xq[t] = fmaf(v0, v0, fmaf(v1, v1, xq[t]));
                s[j] = (short)f2bf(v0);
                s[4 + j] = (short)f2bf(v1);
            }
            afr[t][ks] = s;
        }
    }
    // reduce Sum(x^2) across the 4 quads (each quad holds a disjoint k-range)
    #pragma unroll
    for (int t = 0; t < 2; ++t) { xq[t] += __shfl_xor(xq[t], 16); xq[t] += __shfl_xor(xq[t], 32); }
    // lane holds xn2 for row t*16 + (lane&15); redistribute to C-layout row owner (t*16 + q*4 + r)
    float xn2v[2][4];
    #pragma unroll
    for (int t = 0; t < 2; ++t)
        #pragma unroll
        for (int r = 0; r < 4; ++r) xn2v[t][r] = __shfl(xq[t], q * 4 + r);

    // ---- GEMM: mx = X @ W^T, 16x16x32 bf16 MFMA ----
    f32x4 acc[2][8];
    {
        f32x4 z = {0.0f, 0.0f, 0.0f, 0.0f};
        #pragma unroll
        for (int t = 0; t < 2; ++t)
            #pragma unroll
            for (int nt = 0; nt < 8; ++nt) acc[t][nt] = z;
    }
    #pragma unroll
    for (int nt = 0; nt < 8; ++nt) {
        const float* wrow = Wf + (nt * 16 + c) * 128;   // W row (output col nt*16+c)
        #pragma unroll
        for (int ks = 0; ks < 4; ++ks) {
            // B[k][n] = W[n][k]: lane reads 8 consecutive k from its W row
            f32x4 w0 = *(const f32x4*)(wrow + ks * 32 + q * 8);
            f32x4 w1 = *(const f32x4*)(wrow + ks * 32 + q * 8 + 4);
            short8 bfr;
            #pragma unroll
            for (int j = 0; j < 4; ++j) {
                bfr[j] = (short)f2bf(w0[j]);
                bfr[4 + j] = (short)f2bf(w1[j]);
            }
            acc[0][nt] = __builtin_amdgcn_mfma_f32_16x16x32_bf16(afr[0][ks], bfr, acc[0][nt], 0, 0, 0);
            acc[1][nt] = __builtin_amdgcn_mfma_f32_16x16x32_bf16(afr[1][ks], bfr, acc[1][nt], 0, 0, 0);
        }
    }

    // ---- round-1 reductions over cols: mn2 = sum(mx^2), mhb = sum(mx*hb) ----
    // C layout: col = lane&15 (+16*nt), row = t*16 + q*4 + reg
    float mn2[2][4] = {}, mhb[2][4] = {};
    #pragma unroll
    for (int t = 0; t < 2; ++t)
        #pragma unroll
        for (int nt = 0; nt < 8; ++nt)
            #pragma unroll
            for (int r = 0; r < 4; ++r) {
                float v = acc[t][nt][r];
                mn2[t][r] = fmaf(v, v, mn2[t][r]);
                mhb[t][r] = fmaf(v, hbv[nt], mhb[t][r]);
            }
    #pragma unroll
    for (int m = 1; m <= 8; m <<= 1)
        #pragma unroll
        for (int t = 0; t < 2; ++t)
            #pragma unroll
            for (int r = 0; r < 4; ++r) {
                mn2[t][r] += __shfl_xor(mn2[t][r], m);
                mhb[t][r] += __shfl_xor(mhb[t][r], m);
            }

    // ---- per-row scalar chain (each lane owns its quad's 4+4 rows; redundant across col-lanes) ----
    float A1[2][4], B1[2][4], Gg[2][4], S3[2][4];
    #pragma unroll
    for (int t = 0; t < 2; ++t)
        #pragma unroll
        for (int r = 0; r < 4; ++r) {
            float xn = fmaxf(sqrtf(xn2v[t][r]), MINNORM);
            float mn = fmaxf(sqrtf(mn2[t][r]), MINNORM);
            // mobius_matvec: res = tanh(mx_n/x_n * artanh(x_n)) * mx / mx_n, then proj
            float t1 = tanh_pos(mn * frcp(xn) * artanh_c(xn));
            float rn = fminf(t1, MAXNORM);          // ||res|| after proj
            float f1 = rn * frcp(mn);               // res = f1 * mx  (mx==0 -> res ~ 0)
            float x2 = rn * rn;
            // mobius_add(res, hb): res2 = (A*res + B*hb)/D
            float xy = f1 * mhb[t][r];
            float Aa = 1.0f + 2.0f * xy + hb2;
            float Bb = 1.0f - x2;
            float Dn = fmaxf(1.0f + 2.0f * xy + x2 * hb2, MINNORM);
            float rD = frcp(Dn);
            float a1 = Aa * f1 * rD;                // res2 = a1*mx + b1_*hb
            float b1_ = Bb * rD;
            // ||res2||^2 from known scalars
            float r2n2 = a1 * a1 * mn2[t][r] + 2.0f * a1 * b1_ * mhb[t][r] + b1_ * b1_ * hb2;
            float r2n = sqrtf(fmaxf(r2n2, 0.0f));
            float g = (r2n > MAXNORM) ? (MAXNORM * frcp(r2n)) : 1.0f;   // proj
            float n3 = fmaxf(fminf(r2n, MAXNORM), MINNORM);
            float s3 = artanh_c(n3) * frcp(n3);     // logmap0 scale (>0, commutes with relu)
            A1[t][r] = a1; B1[t][r] = b1_; Gg[t][r] = g; S3[t][r] = s3;
        }

    // ---- round-2 reduction: q2 = sum(max(a1*mx + b1_*hb, 0)^2) ----
    float q2[2][4] = {};
    #pragma unroll
    for (int t = 0; t < 2; ++t)
        #pragma unroll
        for (int nt = 0; nt < 8; ++nt)
            #pragma unroll
            for (int r = 0; r < 4; ++r) {
                float v = fmaf(A1[t][r], acc[t][nt][r], B1[t][r] * hbv[nt]);
                v = fmaxf(v, 0.0f);
                acc[t][nt][r] = v;                  // keep relu'd pre-scale value
                q2[t][r] = fmaf(v, v, q2[t][r]);
            }
    #pragma unroll
    for (int m = 1; m <= 8; m <<= 1)
        #pragma unroll
        for (int t = 0; t < 2; ++t)
            #pragma unroll
            for (int r = 0; r < 4; ++r) q2[t][r] += __shfl_xor(q2[t][r], m);

    // ---- final scale: logmap0-scale * proj-scale folded into expmap0 + proj ----
    float K[2][4];
    #pragma unroll
    for (int t = 0; t < 2; ++t)
        #pragma unroll
        for (int r = 0; r < 4; ++r) {
            float sg = S3[t][r] * Gg[t][r];
            float tn_t = sg * sqrtf(q2[t][r]);      // ||relu(logmap0(res3))||
            float tn = fmaxf(tn_t, MINNORM);
            float t4 = tanh_pos(tn);
            K[t][r] = fminf(t4, MAXNORM) * frcp(tn) * sg;
        }

    // ---- store: out_j = K * relu_val, fp32, direct from C layout ----
    #pragma unroll
    for (int t = 0; t < 2; ++t)
        #pragma unroll
        for (int r = 0; r < 4; ++r) {
            long row = rowbase + t * 16 + q * 4 + r;
            float* orow = Out + row * 128;
            #pragma unroll
            for (int nt = 0; nt < 8; ++nt)
                orow[nt * 16 + c] = K[t][r] * acc[t][nt][r];
        }
}

extern "C" void kernel_launch(void* const* d_in, const int* in_sizes, int n_in,
                              void* d_out, int out_size, void* d_ws, size_t ws_size,
                              hipStream_t stream) {
    const float* X = (const float*)d_in[0];   // fp32 [N,128]
    const float* W = (const float*)d_in[1];   // fp32 [128,128]
    const float* B = (const float*)d_in[2];   // fp32 [128]
    float* Out = (float*)d_out;
    const int N = in_sizes[0] / 128;          // 524288 rows
    const int blocks = N / 128;               // 128 rows per block (4 waves x 32 rows)
    blinear_kernel<<<blocks, 256, 0, stream>>>(X, W, B, Out);
}